// Round 4
// baseline (228.472 us; speedup 1.0000x reference)
//
#include <hip/hip_runtime.h>
#include <hip/hip_bf16.h>
#include <stdint.h>

#define C_DIM 128
#define H_DIM 5

typedef __bf16 bf16x8 __attribute__((ext_vector_type(8)));
typedef float f32x4 __attribute__((ext_vector_type(4)));
typedef float f32x4u __attribute__((ext_vector_type(4), aligned(4)));
typedef int   i32x4u __attribute__((ext_vector_type(4), aligned(4)));

static __device__ __forceinline__ ushort f2bf(float x) {
    __hip_bfloat16 b = __float2bfloat16(x);
    return *reinterpret_cast<ushort*>(&b);
}

// ---------------- K0: conv_A | conv_Bt | wa | count ----------------
__global__ __launch_bounds__(256) void prep0_kernel(
    const float* __restrict__ F, const float* __restrict__ W,
    const float* __restrict__ att_src, const float* __restrict__ att_dst,
    ushort* __restrict__ Abf, ushort* __restrict__ Bt, float* __restrict__ Wa,
    const int* __restrict__ dstArr, int* __restrict__ deg,
    int B1, int B2, int B3, int N, int E) {
    int b = blockIdx.x;
    int tid = threadIdx.x;
    if (b < B1) {
        int t = b * 256 + tid;
        if (t < N * 16) {
            const float4* f4 = reinterpret_cast<const float4*>(F) + (size_t)t * 2;
            float4 v0 = f4[0], v1 = f4[1];
            float vv[8] = {v0.x, v0.y, v0.z, v0.w, v1.x, v1.y, v1.z, v1.w};
            ushort u[8];
#pragma unroll
            for (int i = 0; i < 8; ++i) u[i] = f2bf(vv[i]);
            *reinterpret_cast<uint4*>(Abf + (size_t)t * 8) = *reinterpret_cast<uint4*>(u);
        }
    } else if (b < B2) {
        int t = (b - B1) * 256 + tid;
        if (t < 640 * 128) {
            int c = t >> 7, k = t & 127;
            Bt[t] = f2bf(W[(size_t)k * 640 + c]);
        }
    } else if (b < B3) {
        int t = (b - B2) * 256 + tid;
        if (t < C_DIM * 10) {
            int k = t / 10, j = t % 10;
            int h = j % 5;
            const float* att = ((j < 5) ? att_src : att_dst) + h * C_DIM;
            const float* w = W + (size_t)k * (H_DIM * C_DIM) + h * C_DIM;
            float sum = 0.f;
#pragma unroll 8
            for (int c = 0; c < C_DIM; ++c) sum = fmaf(w[c], att[c], sum);
            Wa[k * 10 + j] = sum;
        }
    } else {
        int e = (b - B3) * 256 + tid;
        if (e < E + N) {
            int i = (e < E) ? dstArr[e] : (e - E);
            atomicAdd(&deg[i], 1);
        }
    }
}

// ---------------- K1: scan (block 0) | alpha (blocks 1..) ----------------
__global__ __launch_bounds__(256) void prep1_kernel(
    const float* __restrict__ F, const float* __restrict__ Wa,
    float* __restrict__ asrc, float* __restrict__ adst,
    const int* __restrict__ deg, int* __restrict__ rowptr, int N) {
    int b = blockIdx.x;
    int tid = threadIdx.x;
    if (b == 0) {
        __shared__ int lds[256];
        const int CH = (N + 255) / 256;
        int begin = tid * CH;
        int end = begin + CH; if (end > N) end = N;
        int sum = 0;
        for (int i = begin; i < end; ++i) sum += deg[i];
        lds[tid] = sum;
        __syncthreads();
        for (int off = 1; off < 256; off <<= 1) {
            int v = 0;
            if (tid >= off) v = lds[tid - off];
            __syncthreads();
            if (tid >= off) lds[tid] += v;
            __syncthreads();
        }
        int base = (tid == 0) ? 0 : lds[tid - 1];
        for (int i = begin; i < end; ++i) {
            rowptr[i] = base;
            base += deg[i];
        }
        if (tid == 255) rowptr[N] = lds[255];
    } else {
        int t = (b - 1) * 256 + tid;
        if (t < N * 10) {
            int n = t / 10, j = t % 10;
            const float* f = F + (size_t)n * C_DIM;
            float sum = 0.f;
#pragma unroll 8
            for (int k = 0; k < C_DIM; ++k) sum = fmaf(f[k], Wa[k * 10 + j], sum);
            if (j < 5) asrc[n * 5 + j] = sum;
            else       adst[n * 5 + (j - 5)] = sum;
        }
    }
}

// ---------------- K2: h = F @ W via bf16 MFMA, 128x64 tile ----------------
__global__ __launch_bounds__(256) void gemm_h_mfma(const ushort* __restrict__ Abf,
                                                   const ushort* __restrict__ Bt,
                                                   ushort* __restrict__ Hout, int M) {
    __shared__ ushort As[128][136];
    __shared__ ushort Bs[64][136];
    int tid = threadIdx.x;
    int row0 = blockIdx.x * 128;
    int col0 = blockIdx.y * 64;
    int seg = tid & 15, rb = tid >> 4;
#pragma unroll
    for (int p = 0; p < 8; ++p) {
        int r = rb + p * 16;
        int gr = row0 + r;
        uint4 v = make_uint4(0u, 0u, 0u, 0u);
        if (gr < M) v = *reinterpret_cast<const uint4*>(Abf + (size_t)gr * 128 + seg * 8);
        *reinterpret_cast<uint4*>(&As[r][seg * 8]) = v;
    }
#pragma unroll
    for (int p = 0; p < 4; ++p) {
        int r = rb + p * 16;
        uint4 v = *reinterpret_cast<const uint4*>(Bt + (size_t)(col0 + r) * 128 + seg * 8);
        *reinterpret_cast<uint4*>(&Bs[r][seg * 8]) = v;
    }
    __syncthreads();

    int wave = tid >> 6, lane = tid & 63;
    int wr = (wave & 1) * 64;
    int wc = (wave >> 1) * 32;
    int lm = lane & 15, lk = (lane >> 4) * 8;
    f32x4 acc[4][2] = {};
#pragma unroll
    for (int kk = 0; kk < 4; ++kk) {
        int k = kk * 32 + lk;
        bf16x8 a[4], bvec[2];
#pragma unroll
        for (int m = 0; m < 4; ++m)
            a[m] = *reinterpret_cast<const bf16x8*>(&As[wr + m * 16 + lm][k]);
#pragma unroll
        for (int n = 0; n < 2; ++n)
            bvec[n] = *reinterpret_cast<const bf16x8*>(&Bs[wc + n * 16 + lm][k]);
#pragma unroll
        for (int m = 0; m < 4; ++m)
#pragma unroll
            for (int n = 0; n < 2; ++n)
                acc[m][n] = __builtin_amdgcn_mfma_f32_16x16x32_bf16(a[m], bvec[n], acc[m][n], 0, 0, 0);
    }
    int r4 = (lane >> 4) * 4;
#pragma unroll
    for (int m = 0; m < 4; ++m) {
#pragma unroll
        for (int r = 0; r < 4; ++r) {
            int grow = row0 + wr + m * 16 + r4 + r;
            if (grow < M) {
#pragma unroll
                for (int n = 0; n < 2; ++n)
                    Hout[(size_t)grow * 640 + col0 + wc + n * 16 + lm] = f2bf(acc[m][n][r]);
            }
        }
    }
}

// ---------------- K3: scatter + per-edge softmax weights into position-planes ----------------
__global__ __launch_bounds__(256) void scatter_w_kernel(
    const int* __restrict__ srcArr, const int* __restrict__ dstArr,
    const int* __restrict__ rowptr, int* __restrict__ cnt, int* __restrict__ col,
    const float* __restrict__ asrc, const float* __restrict__ adst,
    float* __restrict__ wpl, int E, int N, int EN) {
    int e = blockIdx.x * 256 + threadIdx.x;
    if (e >= EN) return;
    int i, s;
    if (e < E) { i = dstArr[e]; s = srcArr[e]; }
    else       { i = e - E;    s = i; }
    int pos = rowptr[i] + atomicAdd(&cnt[i], 1);
    col[pos] = s;
#pragma unroll
    for (int h = 0; h < 5; ++h) {
        float ev = asrc[s * 5 + h] + adst[i * 5 + h];
        ev = (ev > 0.f) ? ev : 0.2f * ev;
        wpl[(size_t)h * EN + pos] = __expf(ev);
    }
}

// ---------------- K4: aggregation; 4 waves/block, 1 wave = 1 node ----------------
// lane = 16*g + m : heads 0-3 -> group g owns channels m*8..m*8+7 of head g.
// head 4: lane l owns channels 2l, 2l+1 (4B load, no replication).
__global__ __launch_bounds__(256, 8) void gat_aggregate(
    const int* __restrict__ rowptr, const int* __restrict__ col,
    const float* __restrict__ wpl, const ushort* __restrict__ hbf,
    const float* __restrict__ features, const float* __restrict__ bias,
    float* __restrict__ out, int N, int EN) {
    int node = blockIdx.x * 4 + (threadIdx.x >> 6);
    if (node >= N) return;  // no __syncthreads below -> safe
    int lane = threadIdx.x & 63;
    int g = lane >> 4, m = lane & 15;
    const float* wg_p = wpl + (size_t)g * EN;
    const float* w4_p = wpl + (size_t)4 * EN;
    const int offA = g * 128 + m * 8;   // ushort offset for head g
    const int offB = 512 + lane * 2;    // ushort offset for head 4 (2 ch/lane)
    int p0 = rowptr[node], p1 = rowptr[node + 1];
    float accG[8] = {};
    float acc4a = 0.f, acc4b = 0.f;
    float sg = 0.f, s4 = 0.f;
    int p = p0;
    for (; p + 4 <= p1; p += 4) {
        i32x4u j4 = *reinterpret_cast<const i32x4u*>(col + p);
        f32x4u wgv = *reinterpret_cast<const f32x4u*>(wg_p + p);
        f32x4u w4v = *reinterpret_cast<const f32x4u*>(w4_p + p);
        uint4 q[4]; uint32_t q4[4];
#pragma unroll
        for (int b = 0; b < 4; ++b) {
            const ushort* hp = hbf + (size_t)j4[b] * 640;
            q[b]  = *reinterpret_cast<const uint4*>(hp + offA);
            q4[b] = *reinterpret_cast<const uint32_t*>(hp + offB);
        }
#pragma unroll
        for (int b = 0; b < 4; ++b) {
            float wg = wgv[b], w4 = w4v[b];
            sg += wg; s4 += w4;
            uint32_t uu[4] = {q[b].x, q[b].y, q[b].z, q[b].w};
#pragma unroll
            for (int i = 0; i < 4; ++i) {
                accG[2 * i]     = fmaf(wg, __uint_as_float(uu[i] << 16), accG[2 * i]);
                accG[2 * i + 1] = fmaf(wg, __uint_as_float(uu[i] & 0xffff0000u), accG[2 * i + 1]);
            }
            acc4a = fmaf(w4, __uint_as_float(q4[b] << 16), acc4a);
            acc4b = fmaf(w4, __uint_as_float(q4[b] & 0xffff0000u), acc4b);
        }
    }
    for (; p < p1; ++p) {
        int j = col[p];
        float wg = wg_p[p], w4 = w4_p[p];
        sg += wg; s4 += w4;
        const ushort* hp = hbf + (size_t)j * 640;
        uint4 q = *reinterpret_cast<const uint4*>(hp + offA);
        uint32_t q4 = *reinterpret_cast<const uint32_t*>(hp + offB);
        uint32_t uu[4] = {q.x, q.y, q.z, q.w};
#pragma unroll
        for (int i = 0; i < 4; ++i) {
            accG[2 * i]     = fmaf(wg, __uint_as_float(uu[i] << 16), accG[2 * i]);
            accG[2 * i + 1] = fmaf(wg, __uint_as_float(uu[i] & 0xffff0000u), accG[2 * i + 1]);
        }
        acc4a = fmaf(w4, __uint_as_float(q4 << 16), acc4a);
        acc4b = fmaf(w4, __uint_as_float(q4 & 0xffff0000u), acc4b);
    }
    float invg = 1.f / (sg + 1e-16f);
    float r[8];
#pragma unroll
    for (int e = 0; e < 8; ++e) r[e] = accG[e] * invg;
#pragma unroll
    for (int e = 0; e < 8; ++e) r[e] += __shfl_xor(r[e], 16, 64);
#pragma unroll
    for (int e = 0; e < 8; ++e) r[e] += __shfl_xor(r[e], 32, 64);
    // fold in head 4: channel m*8+i lives in lane 4m+(i>>1), comp i&1
    float inv4 = 1.f / (s4 + 1e-16f);
#pragma unroll
    for (int i = 0; i < 8; ++i) {
        int srcl = 4 * m + (i >> 1);
        float h4 = __shfl((i & 1) ? acc4b : acc4a, srcl, 64);
        r[i] = fmaf(h4, inv4, r[i]);
    }
    if (g == 0) {
        int c0 = m * 8;
        size_t base = (size_t)node * 128 + c0;
        float4 f0 = *reinterpret_cast<const float4*>(features + base);
        float4 f1 = *reinterpret_cast<const float4*>(features + base + 4);
        float4 b0 = *reinterpret_cast<const float4*>(bias + c0);
        float4 b1 = *reinterpret_cast<const float4*>(bias + c0 + 4);
        float4 o0, o1;
        o0.x = f0.x + b0.x + 0.2f * r[0];
        o0.y = f0.y + b0.y + 0.2f * r[1];
        o0.z = f0.z + b0.z + 0.2f * r[2];
        o0.w = f0.w + b0.w + 0.2f * r[3];
        o1.x = f1.x + b1.x + 0.2f * r[4];
        o1.y = f1.y + b1.y + 0.2f * r[5];
        o1.z = f1.z + b1.z + 0.2f * r[6];
        o1.w = f1.w + b1.w + 0.2f * r[7];
        *reinterpret_cast<float4*>(out + base) = o0;
        *reinterpret_cast<float4*>(out + base + 4) = o1;
    }
}

// ---------------- launch ----------------
static inline char* bump(char*& p, size_t bytes) {
    char* r = p;
    p += (bytes + 255) & ~(size_t)255;
    return r;
}

extern "C" void kernel_launch(void* const* d_in, const int* in_sizes, int n_in,
                              void* d_out, int out_size, void* d_ws, size_t ws_size,
                              hipStream_t stream) {
    const float* features = (const float*)d_in[0];
    const float* W        = (const float*)d_in[1];
    const float* att_src  = (const float*)d_in[2];
    const float* att_dst  = (const float*)d_in[3];
    const float* bias     = (const float*)d_in[4];
    const int*   edges    = (const int*)d_in[5];

    const int N = in_sizes[0] / C_DIM;
    const int E = in_sizes[5] / 2;
    const int EN = E + N;
    const int* srcArr = edges;
    const int* dstArr = edges + E;

    char* p = (char*)d_ws;
    float* Wa     = (float*)bump(p, C_DIM * 10 * sizeof(float));
    float* asrc   = (float*)bump(p, (size_t)N * 5 * sizeof(float));
    float* adst   = (float*)bump(p, (size_t)N * 5 * sizeof(float));
    ushort* hbf   = (ushort*)bump(p, (size_t)N * 640 * sizeof(ushort));
    ushort* Abf   = (ushort*)bump(p, (size_t)N * C_DIM * sizeof(ushort));
    ushort* Bt    = (ushort*)bump(p, 640 * 128 * sizeof(ushort));
    int* deg      = (int*)bump(p, (size_t)2 * N * sizeof(int));
    int* cnt      = deg + N;
    int* rowptr   = (int*)bump(p, (size_t)(N + 1) * sizeof(int));
    int* col      = (int*)bump(p, (size_t)EN * sizeof(int));
    float* wpl    = (float*)bump(p, (size_t)5 * EN * sizeof(float));

    float* out = (float*)d_out;

    hipMemsetAsync(deg, 0, (size_t)2 * N * sizeof(int), stream);

    // K0: conv_A | conv_Bt | wa | count
    const int B1 = (N * 16 + 255) / 256;
    const int B2 = B1 + (640 * 128 + 255) / 256;
    const int B3 = B2 + (C_DIM * 10 + 255) / 256;
    const int G0 = B3 + (EN + 255) / 256;
    prep0_kernel<<<G0, 256, 0, stream>>>(features, W, att_src, att_dst, Abf, Bt, Wa,
                                         dstArr, deg, B1, B2, B3, N, E);
    // K1: scan | alpha
    const int G1 = 1 + (N * 10 + 255) / 256;
    prep1_kernel<<<G1, 256, 0, stream>>>(features, Wa, asrc, adst, deg, rowptr, N);
    // K2: gemm h
    dim3 ggrid((N + 127) / 128, 10);
    gemm_h_mfma<<<ggrid, 256, 0, stream>>>(Abf, Bt, hbf, N);
    // K3: scatter + weights
    scatter_w_kernel<<<(EN + 255) / 256, 256, 0, stream>>>(srcArr, dstArr, rowptr, cnt, col,
                                                           asrc, adst, wpl, E, N, EN);
    // K4: aggregate + epilogue
    gat_aggregate<<<(N + 3) / 4, 256, 0, stream>>>(rowptr, col, wpl, hbf, features, bias,
                                                   out, N, EN);
}

// Round 5
// 164.733 us; speedup vs baseline: 1.3869x; 1.3869x over previous
//
#include <hip/hip_runtime.h>
#include <hip/hip_bf16.h>
#include <stdint.h>

#define C_DIM 128
#define H_DIM 5

typedef __bf16 bf16x8 __attribute__((ext_vector_type(8)));
typedef float f32x4 __attribute__((ext_vector_type(4)));

static __device__ __forceinline__ ushort f2bf(float x) {
    __hip_bfloat16 b = __float2bfloat16(x);
    return *reinterpret_cast<ushort*>(&b);
}

// ---------------- K0: conv_A | conv_Bt | wa | count ----------------
__global__ __launch_bounds__(256) void prep0_kernel(
    const float* __restrict__ F, const float* __restrict__ W,
    const float* __restrict__ att_src, const float* __restrict__ att_dst,
    ushort* __restrict__ Abf, ushort* __restrict__ Bt, float* __restrict__ Wa,
    const int* __restrict__ dstArr, int* __restrict__ deg,
    int B1, int B2, int B3, int N, int E) {
    int b = blockIdx.x;
    int tid = threadIdx.x;
    if (b < B1) {
        int t = b * 256 + tid;
        if (t < N * 16) {
            const float4* f4 = reinterpret_cast<const float4*>(F) + (size_t)t * 2;
            float4 v0 = f4[0], v1 = f4[1];
            float vv[8] = {v0.x, v0.y, v0.z, v0.w, v1.x, v1.y, v1.z, v1.w};
            ushort u[8];
#pragma unroll
            for (int i = 0; i < 8; ++i) u[i] = f2bf(vv[i]);
            *reinterpret_cast<uint4*>(Abf + (size_t)t * 8) = *reinterpret_cast<uint4*>(u);
        }
    } else if (b < B2) {
        int t = (b - B1) * 256 + tid;
        if (t < 640 * 128) {
            int c = t >> 7, k = t & 127;
            Bt[t] = f2bf(W[(size_t)k * 640 + c]);
        }
    } else if (b < B3) {
        int t = (b - B2) * 256 + tid;
        if (t < C_DIM * 10) {
            int k = t / 10, j = t % 10;
            int h = j % 5;
            const float* att = ((j < 5) ? att_src : att_dst) + h * C_DIM;
            const float* w = W + (size_t)k * (H_DIM * C_DIM) + h * C_DIM;
            float sum = 0.f;
#pragma unroll 8
            for (int c = 0; c < C_DIM; ++c) sum = fmaf(w[c], att[c], sum);
            Wa[k * 10 + j] = sum;
        }
    } else {
        int e = (b - B3) * 256 + tid;
        if (e < E + N) {
            int i = (e < E) ? dstArr[e] : (e - E);
            atomicAdd(&deg[i], 1);
        }
    }
}

// ---------------- K1: single-block scan -> rowptr ----------------
__global__ __launch_bounds__(1024) void scan_kernel(const int* __restrict__ deg,
                                                    int* __restrict__ rowptr, int n) {
    __shared__ int lds[1024];
    int t = threadIdx.x;
    const int CH = (n + 1023) / 1024;
    int begin = t * CH;
    int end = begin + CH; if (end > n) end = n;
    int sum = 0;
    for (int i = begin; i < end && i < n; ++i) sum += deg[i];
    lds[t] = sum;
    __syncthreads();
    for (int off = 1; off < 1024; off <<= 1) {
        int v = 0;
        if (t >= off) v = lds[t - off];
        __syncthreads();
        if (t >= off) lds[t] += v;
        __syncthreads();
    }
    int base = (t == 0) ? 0 : lds[t - 1];
    for (int i = begin; i < end && i < n; ++i) {
        rowptr[i] = base;
        base += deg[i];
    }
    if (t == 1023) rowptr[n] = lds[1023];
}

// ---------------- K2: alpha | scatter ----------------
__global__ __launch_bounds__(256) void prep1_kernel(
    const float* __restrict__ F, const float* __restrict__ Wa,
    float* __restrict__ asrc, float* __restrict__ adst,
    const int* __restrict__ srcArr, const int* __restrict__ dstArr,
    const int* __restrict__ rowptr, int* __restrict__ cnt, int* __restrict__ col,
    int B1, int N, int E) {
    int b = blockIdx.x;
    int tid = threadIdx.x;
    if (b < B1) {
        int t = b * 256 + tid;
        if (t < N * 10) {
            int n = t / 10, j = t % 10;
            const float* f = F + (size_t)n * C_DIM;
            float sum = 0.f;
#pragma unroll 8
            for (int k = 0; k < C_DIM; ++k) sum = fmaf(f[k], Wa[k * 10 + j], sum);
            if (j < 5) asrc[n * 5 + j] = sum;
            else       adst[n * 5 + (j - 5)] = sum;
        }
    } else {
        int e = (b - B1) * 256 + tid;
        if (e < E + N) {
            int i, s;
            if (e < E) { i = dstArr[e]; s = srcArr[e]; }
            else       { i = e - E;    s = i; }
            int pos = rowptr[i] + atomicAdd(&cnt[i], 1);
            col[pos] = s;
        }
    }
}

// ---------------- K3: h = F @ W via bf16 MFMA, 128x64 tile ----------------
__global__ __launch_bounds__(256) void gemm_h_mfma(const ushort* __restrict__ Abf,
                                                   const ushort* __restrict__ Bt,
                                                   ushort* __restrict__ Hout, int M) {
    __shared__ ushort As[128][136];
    __shared__ ushort Bs[64][136];
    int tid = threadIdx.x;
    int row0 = blockIdx.x * 128;
    int col0 = blockIdx.y * 64;
    int seg = tid & 15, rb = tid >> 4;
#pragma unroll
    for (int p = 0; p < 8; ++p) {
        int r = rb + p * 16;
        int gr = row0 + r;
        uint4 v = make_uint4(0u, 0u, 0u, 0u);
        if (gr < M) v = *reinterpret_cast<const uint4*>(Abf + (size_t)gr * 128 + seg * 8);
        *reinterpret_cast<uint4*>(&As[r][seg * 8]) = v;
    }
#pragma unroll
    for (int p = 0; p < 4; ++p) {
        int r = rb + p * 16;
        uint4 v = *reinterpret_cast<const uint4*>(Bt + (size_t)(col0 + r) * 128 + seg * 8);
        *reinterpret_cast<uint4*>(&Bs[r][seg * 8]) = v;
    }
    __syncthreads();

    int wave = tid >> 6, lane = tid & 63;
    int wr = (wave & 1) * 64;
    int wc = (wave >> 1) * 32;
    int lm = lane & 15, lk = (lane >> 4) * 8;
    f32x4 acc[4][2] = {};
#pragma unroll
    for (int kk = 0; kk < 4; ++kk) {
        int k = kk * 32 + lk;
        bf16x8 a[4], bvec[2];
#pragma unroll
        for (int m = 0; m < 4; ++m)
            a[m] = *reinterpret_cast<const bf16x8*>(&As[wr + m * 16 + lm][k]);
#pragma unroll
        for (int n = 0; n < 2; ++n)
            bvec[n] = *reinterpret_cast<const bf16x8*>(&Bs[wc + n * 16 + lm][k]);
#pragma unroll
        for (int m = 0; m < 4; ++m)
#pragma unroll
            for (int n = 0; n < 2; ++n)
                acc[m][n] = __builtin_amdgcn_mfma_f32_16x16x32_bf16(a[m], bvec[n], acc[m][n], 0, 0, 0);
    }
    int r4 = (lane >> 4) * 4;
#pragma unroll
    for (int m = 0; m < 4; ++m) {
#pragma unroll
        for (int r = 0; r < 4; ++r) {
            int grow = row0 + wr + m * 16 + r4 + r;
            if (grow < M) {
#pragma unroll
                for (int n = 0; n < 2; ++n)
                    Hout[(size_t)grow * 640 + col0 + wc + n * 16 + lm] = f2bf(acc[m][n][r]);
            }
        }
    }
}

// ---------------- K4: aggregation; 4 independent waves/block, 1 wave = 1 node ----------------
// lane = 16*g + m : heads 0-3 -> group g owns channels m*8..m*8+7 of head g (16B load).
// head 4: lane l owns channels 2l,2l+1 (4B load, no replication); shfl fold in epilogue.
__global__ __launch_bounds__(256, 6) void gat_aggregate(
    const int* __restrict__ rowptr, const int* __restrict__ col,
    const float* __restrict__ asrc, const float* __restrict__ adst,
    const ushort* __restrict__ hbf,
    const float* __restrict__ features, const float* __restrict__ bias,
    float* __restrict__ out, int N) {
    int node = blockIdx.x * 4 + (threadIdx.x >> 6);
    if (node >= N) return;  // no __syncthreads below -> safe
    int lane = threadIdx.x & 63;
    int g = lane >> 4, m = lane & 15;
    float adg = adst[node * 5 + g];
    float ad4 = adst[node * 5 + 4];
    const int offA = g * 128 + m * 8;   // ushort offset, head g
    const int offB = 512 + lane * 2;    // ushort offset, head 4 (2 ch/lane)
    int p0 = rowptr[node], p1 = rowptr[node + 1];
    float accG[8] = {};
    float acc4a = 0.f, acc4b = 0.f;
    float sg = 0.f, s4 = 0.f;
    int p = p0;
    for (; p + 4 <= p1; p += 4) {
        int jj[4];
#pragma unroll
        for (int b = 0; b < 4; ++b) jj[b] = col[p + b];
        uint4 q[4]; uint32_t q4[4];
#pragma unroll
        for (int b = 0; b < 4; ++b) {
            const ushort* hp = hbf + (size_t)jj[b] * 640;
            q[b]  = *reinterpret_cast<const uint4*>(hp + offA);
            q4[b] = *reinterpret_cast<const uint32_t*>(hp + offB);
        }
#pragma unroll
        for (int b = 0; b < 4; ++b) {
            float eg = asrc[jj[b] * 5 + g] + adg;
            float e4 = asrc[jj[b] * 5 + 4] + ad4;
            eg = (eg > 0.f) ? eg : 0.2f * eg;
            e4 = (e4 > 0.f) ? e4 : 0.2f * e4;
            float wg = __expf(eg), w4 = __expf(e4);
            sg += wg; s4 += w4;
            uint32_t uu[4] = {q[b].x, q[b].y, q[b].z, q[b].w};
#pragma unroll
            for (int i = 0; i < 4; ++i) {
                accG[2 * i]     = fmaf(wg, __uint_as_float(uu[i] << 16), accG[2 * i]);
                accG[2 * i + 1] = fmaf(wg, __uint_as_float(uu[i] & 0xffff0000u), accG[2 * i + 1]);
            }
            acc4a = fmaf(w4, __uint_as_float(q4[b] << 16), acc4a);
            acc4b = fmaf(w4, __uint_as_float(q4[b] & 0xffff0000u), acc4b);
        }
    }
    for (; p < p1; ++p) {
        int j = col[p];
        float eg = asrc[j * 5 + g] + adg;
        float e4 = asrc[j * 5 + 4] + ad4;
        eg = (eg > 0.f) ? eg : 0.2f * eg;
        e4 = (e4 > 0.f) ? e4 : 0.2f * e4;
        float wg = __expf(eg), w4 = __expf(e4);
        sg += wg; s4 += w4;
        const ushort* hp = hbf + (size_t)j * 640;
        uint4 q = *reinterpret_cast<const uint4*>(hp + offA);
        uint32_t q4 = *reinterpret_cast<const uint32_t*>(hp + offB);
        uint32_t uu[4] = {q.x, q.y, q.z, q.w};
#pragma unroll
        for (int i = 0; i < 4; ++i) {
            accG[2 * i]     = fmaf(wg, __uint_as_float(uu[i] << 16), accG[2 * i]);
            accG[2 * i + 1] = fmaf(wg, __uint_as_float(uu[i] & 0xffff0000u), accG[2 * i + 1]);
        }
        acc4a = fmaf(w4, __uint_as_float(q4 << 16), acc4a);
        acc4b = fmaf(w4, __uint_as_float(q4 & 0xffff0000u), acc4b);
    }
    float invg = 1.f / (sg + 1e-16f);
    float r[8];
#pragma unroll
    for (int e = 0; e < 8; ++e) r[e] = accG[e] * invg;
#pragma unroll
    for (int e = 0; e < 8; ++e) r[e] += __shfl_xor(r[e], 16, 64);
#pragma unroll
    for (int e = 0; e < 8; ++e) r[e] += __shfl_xor(r[e], 32, 64);
    // fold in head 4: channel m*8+i lives in lane 4m+(i>>1), comp i&1
    float inv4 = 1.f / (s4 + 1e-16f);
#pragma unroll
    for (int i = 0; i < 8; ++i) {
        int srcl = 4 * m + (i >> 1);
        float h4 = __shfl((i & 1) ? acc4b : acc4a, srcl, 64);
        r[i] = fmaf(h4, inv4, r[i]);
    }
    if (g == 0) {
        int c0 = m * 8;
        size_t base = (size_t)node * 128 + c0;
        float4 f0 = *reinterpret_cast<const float4*>(features + base);
        float4 f1 = *reinterpret_cast<const float4*>(features + base + 4);
        float4 b0 = *reinterpret_cast<const float4*>(bias + c0);
        float4 b1 = *reinterpret_cast<const float4*>(bias + c0 + 4);
        float4 o0, o1;
        o0.x = f0.x + b0.x + 0.2f * r[0];
        o0.y = f0.y + b0.y + 0.2f * r[1];
        o0.z = f0.z + b0.z + 0.2f * r[2];
        o0.w = f0.w + b0.w + 0.2f * r[3];
        o1.x = f1.x + b1.x + 0.2f * r[4];
        o1.y = f1.y + b1.y + 0.2f * r[5];
        o1.z = f1.z + b1.z + 0.2f * r[6];
        o1.w = f1.w + b1.w + 0.2f * r[7];
        *reinterpret_cast<float4*>(out + base) = o0;
        *reinterpret_cast<float4*>(out + base + 4) = o1;
    }
}

// ---------------- launch ----------------
static inline char* bump(char*& p, size_t bytes) {
    char* r = p;
    p += (bytes + 255) & ~(size_t)255;
    return r;
}

extern "C" void kernel_launch(void* const* d_in, const int* in_sizes, int n_in,
                              void* d_out, int out_size, void* d_ws, size_t ws_size,
                              hipStream_t stream) {
    const float* features = (const float*)d_in[0];
    const float* W        = (const float*)d_in[1];
    const float* att_src  = (const float*)d_in[2];
    const float* att_dst  = (const float*)d_in[3];
    const float* bias     = (const float*)d_in[4];
    const int*   edges    = (const int*)d_in[5];

    const int N = in_sizes[0] / C_DIM;
    const int E = in_sizes[5] / 2;
    const int EN = E + N;
    const int* srcArr = edges;
    const int* dstArr = edges + E;

    char* p = (char*)d_ws;
    float* Wa     = (float*)bump(p, C_DIM * 10 * sizeof(float));
    float* asrc   = (float*)bump(p, (size_t)N * 5 * sizeof(float));
    float* adst   = (float*)bump(p, (size_t)N * 5 * sizeof(float));
    ushort* hbf   = (ushort*)bump(p, (size_t)N * 640 * sizeof(ushort));
    ushort* Abf   = (ushort*)bump(p, (size_t)N * C_DIM * sizeof(ushort));
    ushort* Bt    = (ushort*)bump(p, 640 * 128 * sizeof(ushort));
    int* deg      = (int*)bump(p, (size_t)2 * N * sizeof(int));
    int* cnt      = deg + N;
    int* rowptr   = (int*)bump(p, (size_t)(N + 1) * sizeof(int));
    int* col      = (int*)bump(p, (size_t)EN * sizeof(int));

    float* out = (float*)d_out;

    hipMemsetAsync(deg, 0, (size_t)2 * N * sizeof(int), stream);

    // K0: conv_A | conv_Bt | wa | count
    const int B1 = (N * 16 + 255) / 256;
    const int B2 = B1 + (640 * 128 + 255) / 256;
    const int B3 = B2 + (C_DIM * 10 + 255) / 256;
    const int G0 = B3 + (EN + 255) / 256;
    prep0_kernel<<<G0, 256, 0, stream>>>(features, W, att_src, att_dst, Abf, Bt, Wa,
                                         dstArr, deg, B1, B2, B3, N, E);
    // K1: scan
    scan_kernel<<<1, 1024, 0, stream>>>(deg, rowptr, N);
    // K2: alpha | scatter
    const int A1 = (N * 10 + 255) / 256;
    const int G1 = A1 + (EN + 255) / 256;
    prep1_kernel<<<G1, 256, 0, stream>>>(features, Wa, asrc, adst, srcArr, dstArr,
                                         rowptr, cnt, col, A1, N, E);
    // K3: gemm h
    dim3 ggrid((N + 127) / 128, 10);
    gemm_h_mfma<<<ggrid, 256, 0, stream>>>(Abf, Bt, hbf, N);
    // K4: aggregate + epilogue
    gat_aggregate<<<(N + 3) / 4, 256, 0, stream>>>(rowptr, col, asrc, adst, hbf, features,
                                                   bias, out, N);
}